// Round 5
// baseline (869.322 us; speedup 1.0000x reference)
//
#include <hip/hip_runtime.h>
#include <stdint.h>

#define EMB 64
#define BN_EPS 1e-5f
#define TB_STRIDE 65   // k_mm scalar-LDS tile stride
#define TS 68          // k_aggmm1 tile stride (rows 16B-aligned for float4 LDS ops)

// ---------------- zero init (ws is poisoned 0xAA every call) ----------------
__global__ void k_zero(int* __restrict__ counts, float* __restrict__ stats,
                       int* __restrict__ gcur, int cap, int n, int nstats) {
    int i = blockIdx.x * blockDim.x + threadIdx.x;
    if (i < n) counts[i] = 0;
    if (i < nstats) stats[i] = 0.0f;
    if (i < 8) gcur[i] = i * cap;
}

// ---------------- phase A: edge partition into 8 XCD-group lists + histogram --
// Each block owns a 4096-edge chunk; compacts edges per group into contiguous
// runs (full-line writes). Also does the per-dst histogram (fused k_hist).
__global__ void __launch_bounds__(256) k_partA(
        const int* __restrict__ ei, const float* __restrict__ ew,
        int* __restrict__ gcur, int* __restrict__ counts,
        int2* __restrict__ pG, unsigned short* __restrict__ bG, int E) {
    __shared__ int lcnt[8], lbase[8], loff[8];
    const int tid = threadIdx.x;
    const int c0 = blockIdx.x * 4096;
    if (tid < 8) lcnt[tid] = 0;
    __syncthreads();
    int src[16], dst[16], g[16];
    float wt[16];
#pragma unroll
    for (int i = 0; i < 16; i++) {
        int e = c0 + i * 256 + tid;
        if (e < E) {
            dst[i] = ei[E + e];
            src[i] = ei[e];
            wt[i] = ew[e];
            g[i] = (dst[i] >> 6) & 7;
            atomicAdd(&lcnt[g[i]], 1);
            atomicAdd(&counts[dst[i]], 1);
        } else g[i] = -1;
    }
    __syncthreads();
    if (tid < 8) { lbase[tid] = atomicAdd(&gcur[tid], lcnt[tid]); loff[tid] = 0; }
    __syncthreads();
#pragma unroll
    for (int i = 0; i < 16; i++) {
        if (g[i] >= 0) {
            int pos = lbase[g[i]] + atomicAdd(&loff[g[i]], 1);
            pG[pos] = make_int2(src[i] | ((dst[i] & 63) << 20), __float_as_int(wt[i]));
            bG[pos] = (unsigned short)(dst[i] >> 6);
        }
    }
}

// ---------------- CSR row-offset scan (over counts) ----------------
__global__ void k_scanA(const int* __restrict__ counts, int* __restrict__ bsum, int n) {
    __shared__ int a[256];
    int t = threadIdx.x;
    int i = blockIdx.x * 256 + t;
    a[t] = (i < n) ? counts[i] : 0;
    __syncthreads();
    for (int off = 128; off >= 1; off >>= 1) {
        if (t < off) a[t] += a[t + off];
        __syncthreads();
    }
    if (t == 0) bsum[blockIdx.x] = a[0];
}

__global__ void k_scanB(int* __restrict__ bsum, int nb) {
    __shared__ int a[256];
    __shared__ int carry;
    int t = threadIdx.x;
    if (t == 0) carry = 0;
    __syncthreads();
    for (int base = 0; base < nb; base += 256) {
        int v = (base + t < nb) ? bsum[base + t] : 0;
        a[t] = v;
        __syncthreads();
        for (int off = 1; off < 256; off <<= 1) {
            int x = (t >= off) ? a[t - off] : 0;
            __syncthreads();
            a[t] += x;
            __syncthreads();
        }
        int excl = carry + (t ? a[t - 1] : 0);
        int tot  = carry + a[255];
        if (base + t < nb) bsum[base + t] = excl;
        __syncthreads();
        if (t == 0) carry = tot;
        __syncthreads();
    }
}

__global__ void k_scanC(const int* __restrict__ counts, const int* __restrict__ boff,
                        int* __restrict__ rowst, int* __restrict__ cursor, int n) {
    __shared__ int a[256];
    int t = threadIdx.x;
    int i = blockIdx.x * 256 + t;
    int v = (i < n) ? counts[i] : 0;
    a[t] = v;
    __syncthreads();
    for (int off = 1; off < 256; off <<= 1) {
        int x = (t >= off) ? a[t - off] : 0;
        __syncthreads();
        a[t] += x;
        __syncthreads();
    }
    int excl = boff[blockIdx.x] + (t ? a[t - 1] : 0);
    if (i < n) { rowst[i] = excl; cursor[i] = excl; }
}

// ---------------- phase B: per-group scatter to final CSR positions ----------
// Blocks with blockIdx&7==g stream ONLY group g's compacted list (~1.2MB/XCD),
// so each pairs line is filled by one XCD's L2 with no competing stream thrash.
__global__ void k_partB(const int* __restrict__ gcur, const int2* __restrict__ pG,
                        const unsigned short* __restrict__ bG,
                        int* __restrict__ cursor, int2* __restrict__ pairs, int cap) {
    const int g = blockIdx.x & 7;
    const int bg = blockIdx.x >> 3;
    const int nb = gridDim.x >> 3;
    const int endv = gcur[g];
    for (int s = g * cap + bg * blockDim.x + threadIdx.x; s < endv;
         s += nb * blockDim.x) {
        int2 pk = pG[s];
        int dst = ((int)bG[s]) * 64 + ((pk.x >> 20) & 63);
        int src = pk.x & 0xFFFFF;
        int pos = atomicAdd(&cursor[dst], 1);
        pairs[pos] = make_int2(src, pk.y);
    }
}

// ---------------- fused aggregation + mm1 + stats1 -------------------------
// Block = 4 waves = one 64-node tile. Phase1: wave w aggregates nodes
// [w*16,w*16+16) (lane=feature, scalarized CSR walk) into LDS tile.
// Phase2: lane=node row -> VGPRs. Phase3: wave w computes cols [w*16,+16).
// Phase4: stats from output tile + coalesced flush.
__global__ void __launch_bounds__(256) k_aggmm1(
        const float* __restrict__ h, const int* __restrict__ rowst,
        const int* __restrict__ counts, const int2* __restrict__ pairs,
        const float* __restrict__ W, const float* __restrict__ bias,
        float* __restrict__ out, float* __restrict__ st_out, int N) {
    __shared__ float tb[64 * TS];
    __shared__ float st_part[128];
    const int tid = threadIdx.x;
    const int lane = tid & 63;
    const int wv = tid >> 6;
    if (tid < 128) st_part[tid] = 0.f;
    const int node0 = blockIdx.x * 64;

    // phase 1: aggregate (incl. self term)
    for (int i = 0; i < 16; i++) {
        int nl = wv * 16 + i;
        int node = node0 + nl;
        float a0 = 0.f, a1 = 0.f, a2 = 0.f, a3 = 0.f;
        if (node < N) {
            int un = __builtin_amdgcn_readfirstlane(node);
            int s = rowst[un];
            int end = s + counts[un];
            a0 = h[(size_t)un * EMB + lane];   // self
            int e = s;
            for (; e + 3 < end; e += 4) {
                int2 p0 = pairs[e], p1 = pairs[e + 1], p2 = pairs[e + 2], p3 = pairs[e + 3];
                float v0 = h[(size_t)p0.x * EMB + lane];
                float v1 = h[(size_t)p1.x * EMB + lane];
                float v2 = h[(size_t)p2.x * EMB + lane];
                float v3 = h[(size_t)p3.x * EMB + lane];
                a0 = fmaf(__int_as_float(p0.y), v0, a0);
                a1 = fmaf(__int_as_float(p1.y), v1, a1);
                a2 = fmaf(__int_as_float(p2.y), v2, a2);
                a3 = fmaf(__int_as_float(p3.y), v3, a3);
            }
            for (; e < end; e++) {
                int2 p = pairs[e];
                a0 = fmaf(__int_as_float(p.y), h[(size_t)p.x * EMB + lane], a0);
            }
        }
        tb[nl * TS + lane] = ((a0 + a1) + (a2 + a3));
    }
    __syncthreads();

    // phase 2: lane = node; load full row to VGPRs (stride-68 rows: aligned b128)
    float row[EMB];
    {
        const float4* r4 = (const float4*)(tb + lane * TS);
#pragma unroll
        for (int i = 0; i < 16; i++) {
            float4 v = r4[i];
            row[4 * i + 0] = v.x; row[4 * i + 1] = v.y;
            row[4 * i + 2] = v.z; row[4 * i + 3] = v.w;
        }
    }
    __syncthreads();

    // phase 3: wave wv computes output cols [wv*16, wv*16+16)
    const bool valid = (node0 + lane) < N;
    for (int jc = 0; jc < 2; jc++) {
        int j0 = wv * 16 + jc * 8;   // uniform per wave
        float acc[8];
#pragma unroll
        for (int k = 0; k < 8; k++) acc[k] = bias[j0 + k];
#pragma unroll
        for (int f = 0; f < EMB; f++) {
            const float* wr = W + f * EMB + j0;   // uniform -> s_load
#pragma unroll
            for (int k = 0; k < 8; k++) acc[k] = fmaf(row[f], wr[k], acc[k]);
        }
#pragma unroll
        for (int k = 0; k < 8; k++)
            tb[lane * TS + j0 + k] = valid ? acc[k] : 0.f;
    }
    __syncthreads();

    // phase 4: per-feature stats of output tile (lane = feature)
    float s_sum = 0.f, s_sq = 0.f;
#pragma unroll 4
    for (int i = 0; i < 16; i++) {
        float v = tb[(wv * 16 + i) * TS + lane];
        s_sum += v;
        s_sq = fmaf(v, v, s_sq);
    }
    atomicAdd(&st_part[lane], s_sum);
    atomicAdd(&st_part[64 + lane], s_sq);

    // coalesced flush
    float4* out4 = (float4*)(out + (size_t)node0 * EMB);
#pragma unroll
    for (int it = 0; it < 4; it++) {
        int flat4 = it * 256 + tid;
        int nsub = flat4 >> 4;
        int c4 = flat4 & 15;
        if (node0 + nsub < N)
            out4[flat4] = *(const float4*)(tb + nsub * TS + c4 * 4);
    }
    __syncthreads();
    if (tid < 128) atomicAdd(&st_out[tid], st_part[tid]);
}

// ---------------- matmul (encoder / mm2): wave = 64 nodes x 64 cols --------
template <bool BN_IN, bool DO_STATS>
__global__ void __launch_bounds__(128) k_mm(
                     const float* __restrict__ in, const float* __restrict__ W,
                     const float* __restrict__ bias, const float* __restrict__ stats,
                     const float* __restrict__ g, const float* __restrict__ be,
                     float invN, float* __restrict__ out, float* __restrict__ st_out,
                     int N) {
    __shared__ float tilebuf[2][64 * TB_STRIDE];
    __shared__ float st_part[128];
    const int tid = threadIdx.x;
    const int lane = tid & 63;
    float* tb = tilebuf[tid >> 6];
    if (DO_STATS) {
        st_part[tid] = 0.f;
        __syncthreads();
    }
    float s_sum = 0.f, s_sq = 0.f;

    int wv = (blockIdx.x * blockDim.x + tid) >> 6;
    const int nwv = (gridDim.x * blockDim.x) >> 6;
    const int ntiles = (N + 63) >> 6;
    for (int tile = wv; tile < ntiles; tile += nwv) {
        int utile = __builtin_amdgcn_readfirstlane(tile);
        int node = utile * 64 + lane;
        bool valid = node < N;

        float row[EMB];
        if (valid) {
            const float4* in4 = (const float4*)(in + (size_t)node * EMB);
#pragma unroll
            for (int i = 0; i < 16; i++) {
                float4 v = in4[i];
                row[4 * i + 0] = v.x; row[4 * i + 1] = v.y;
                row[4 * i + 2] = v.z; row[4 * i + 3] = v.w;
            }
        } else {
#pragma unroll
            for (int i = 0; i < EMB; i++) row[i] = 0.f;
        }

        if (BN_IN) {
#pragma unroll
            for (int f = 0; f < EMB; f++) {
                float m  = stats[f] * invN;
                float va = fmaf(stats[EMB + f], invN, -m * m);
                float rs = rsqrtf(va + BN_EPS);
                float sc = rs * g[f];
                float sh = fmaf(-m, sc, be[f]);
                row[f] = fmaxf(0.f, fmaf(row[f], sc, sh));
            }
        }

        for (int jc = 0; jc < 8; jc++) {
            int j0 = jc * 8;
            float acc[8];
#pragma unroll
            for (int k = 0; k < 8; k++) acc[k] = bias[j0 + k];
#pragma unroll
            for (int f = 0; f < EMB; f++) {
                const float* wr = W + f * EMB + j0;   // uniform -> s_load
#pragma unroll
                for (int k = 0; k < 8; k++) acc[k] = fmaf(row[f], wr[k], acc[k]);
            }
#pragma unroll
            for (int k = 0; k < 8; k++)
                tb[lane * TB_STRIDE + j0 + k] = valid ? acc[k] : 0.f;
        }

        if (DO_STATS) {
#pragma unroll 8
            for (int nn = 0; nn < 64; nn++) {
                float v = tb[nn * TB_STRIDE + lane];
                s_sum += v;
                s_sq = fmaf(v, v, s_sq);
            }
        }

        const int tbase = utile * 64;
        float4* out4 = (float4*)out + (size_t)tbase * 16;
#pragma unroll
        for (int it = 0; it < 16; it++) {
            int flat4 = it * 64 + lane;
            int nsub = flat4 >> 4;
            int c4 = flat4 & 15;
            if (tbase + nsub < N) {
                const float* s4 = tb + nsub * TB_STRIDE + c4 * 4;
                out4[flat4] = make_float4(s4[0], s4[1], s4[2], s4[3]);
            }
        }
    }

    if (DO_STATS) {
        atomicAdd(&st_part[lane], s_sum);
        atomicAdd(&st_part[64 + lane], s_sq);
        __syncthreads();
        if (tid < 128) atomicAdd(&st_out[tid], st_part[tid]);
    }
}

// ---------------- outer BN + relu + residual ----------------
__global__ void k_bnres(const float* __restrict__ u, const float* __restrict__ st,
                        const float* __restrict__ g, const float* __restrict__ be,
                        const float* __restrict__ hin, float* __restrict__ hout,
                        float invN, int total4) {
    int stride = gridDim.x * blockDim.x;
    for (int i4 = blockIdx.x * blockDim.x + threadIdx.x; i4 < total4; i4 += stride) {
        int c = i4 & 15;
        float4 uv = ((const float4*)u)[i4];
        float4 hv = ((const float4*)hin)[i4];
        float4 sv = ((const float4*)st)[c];
        float4 qv = ((const float4*)(st + EMB))[c];
        float4 gv = ((const float4*)g)[c];
        float4 bv = ((const float4*)be)[c];
        float4 o;
#define BNR(comp)                                                     \
        {                                                             \
            float m  = sv.comp * invN;                                \
            float va = fmaf(qv.comp, invN, -m * m);                   \
            float rs = rsqrtf(va + BN_EPS);                           \
            float sc = rs * gv.comp;                                  \
            float sh = fmaf(-m, sc, bv.comp);                         \
            float r  = fmaxf(0.f, fmaf(uv.comp, sc, sh));             \
            o.comp = r + hv.comp;                                     \
        }
        BNR(x) BNR(y) BNR(z) BNR(w)
#undef BNR
        ((float4*)hout)[i4] = o;
    }
}

// ---------------- launcher ----------------
extern "C" void kernel_launch(void* const* d_in, const int* in_sizes, int n_in,
                              void* d_out, int out_size, void* d_ws, size_t ws_size,
                              hipStream_t stream) {
    const float* x     = (const float*)d_in[0];
    const int*   ei    = (const int*)d_in[1];
    const float* ew    = (const float*)d_in[3];
    const float* ae_w  = (const float*)d_in[4];
    const float* ae_b  = (const float*)d_in[5];
    const float* W1    = (const float*)d_in[6];
    const float* b1    = (const float*)d_in[7];
    const float* g1    = (const float*)d_in[8];
    const float* be1   = (const float*)d_in[9];
    const float* W2    = (const float*)d_in[10];
    const float* b2    = (const float*)d_in[11];
    const float* g_out = (const float*)d_in[12];
    const float* be_out= (const float*)d_in[13];

    const int N = in_sizes[0] / EMB;
    const int E = in_sizes[3];
    const int L = in_sizes[6] / (EMB * EMB);
    const float invN = 1.0f / (float)N;

    uintptr_t p = (uintptr_t)d_ws;
    auto alloc = [&](size_t bytes) -> void* {
        p = (p + 255) & ~(uintptr_t)255;
        void* r = (void*)p;
        p += bytes;
        return r;
    };
    float* h     = (float*)alloc((size_t)N * EMB * 4);
    float* bufa  = (float*)alloc((size_t)N * EMB * 4);  // also hosts group lists
    float* buft  = (float*)alloc((size_t)N * EMB * 4);
    int*   counts= (int*)alloc((size_t)N * 4);
    int*   rowst = (int*)alloc((size_t)N * 4);
    int*   cursor= (int*)alloc((size_t)N * 4);
    const int NB = (N + 255) / 256;
    int*   bsum  = (int*)alloc((size_t)NB * 4);
    int2*  pairs = (int2*)alloc((size_t)E * 8);
    float* stats = (float*)alloc((size_t)L * 2 * 2 * EMB * 4);
    int*   gcur  = (int*)alloc(8 * 4);
    (void)ws_size; (void)n_in; (void)out_size;

    // group-list capacity: E/8 + slack, lists carved inside bufa (dead until mm2)
    const int CAP = ((E / 8 + 8192) + 255) & ~255;
    int2* pG = (int2*)bufa;                               // 8*CAP*8 bytes
    unsigned short* bG = (unsigned short*)((char*)bufa + (size_t)8 * CAP * 8);

    const int nstats = L * 2 * 2 * EMB;
    int zgrid = ((N > nstats ? N : nstats) + 255) / 256;
    hipLaunchKernelGGL(k_zero, dim3(zgrid), dim3(256), 0, stream,
                       counts, stats, gcur, CAP, N, nstats);

    const int ntiles = (N + 63) / 64;
    const int mmgrid = (ntiles + 1) / 2;
    // encoder: h = x @ ae_w + ae_b
    hipLaunchKernelGGL((k_mm<false, false>), dim3(mmgrid), dim3(128), 0, stream,
                       x, ae_w, ae_b, (const float*)nullptr, (const float*)nullptr,
                       (const float*)nullptr, 0.f, h, (float*)nullptr, N);

    // CSR build: partition -> scans -> group scatter
    hipLaunchKernelGGL(k_partA, dim3((E + 4095) / 4096), dim3(256), 0, stream,
                       ei, ew, gcur, counts, pG, bG, E);
    hipLaunchKernelGGL(k_scanA, dim3(NB), dim3(256), 0, stream, counts, bsum, N);
    hipLaunchKernelGGL(k_scanB, dim3(1),  dim3(256), 0, stream, bsum, NB);
    hipLaunchKernelGGL(k_scanC, dim3(NB), dim3(256), 0, stream, counts, bsum, rowst, cursor, N);
    hipLaunchKernelGGL(k_partB, dim3(512), dim3(256), 0, stream,
                       gcur, pG, bG, cursor, pairs, CAP);

    for (int l = 0; l < L; l++) {
        float* stats1 = stats + (size_t)(l * 2 + 0) * 2 * EMB;
        float* stats2 = stats + (size_t)(l * 2 + 1) * 2 * EMB;

        // t = (agg+h) @ W1 + b1   (+stats1)  — fused
        hipLaunchKernelGGL(k_aggmm1, dim3(ntiles), dim3(256), 0, stream,
                           h, rowst, counts, pairs,
                           W1 + (size_t)l * EMB * EMB, b1 + (size_t)l * EMB,
                           buft, stats1, N);
        // u = relu(bn1(t)) @ W2 + b2   (+stats2)
        hipLaunchKernelGGL((k_mm<true, true>), dim3(mmgrid), dim3(128), 0, stream,
                           buft, W2 + (size_t)l * EMB * EMB, b2 + (size_t)l * EMB,
                           stats1, g1 + (size_t)l * EMB, be1 + (size_t)l * EMB,
                           invN, bufa, stats2, N);
        // h = relu(bn2(u)) + h
        float* hout = (l == L - 1) ? (float*)d_out : h;
        hipLaunchKernelGGL(k_bnres, dim3(1024), dim3(256), 0, stream,
                           bufa, stats2, g_out + (size_t)l * EMB, be_out + (size_t)l * EMB,
                           h, hout, invN, N * 16);
    }
}

// Round 6
// 598.316 us; speedup vs baseline: 1.4529x; 1.4529x over previous
//
#include <hip/hip_runtime.h>
#include <stdint.h>

#define EMB 64
#define BN_EPS 1e-5f
#define TB_STRIDE 65

__device__ __forceinline__ unsigned short f2b(float x) {
    unsigned u = __float_as_uint(x);
    u += 0x7FFFu + ((u >> 16) & 1u);   // round-to-nearest-even
    return (unsigned short)(u >> 16);
}
__device__ __forceinline__ float b2f(unsigned short v) {
    return __uint_as_float(((unsigned)v) << 16);
}

// ---------------- zero init (ws is poisoned 0xAA every call) ----------------
__global__ void k_zero(int* __restrict__ counts, float* __restrict__ stats,
                       int n, int nstats) {
    int i = blockIdx.x * blockDim.x + threadIdx.x;
    if (i < n) counts[i] = 0;
    if (i < nstats) stats[i] = 0.0f;
}

// ---------------- CSR build ----------------
__global__ void k_hist(const int* __restrict__ ei, int* __restrict__ counts, int E) {
    int stride = gridDim.x * blockDim.x;
    for (int e = blockIdx.x * blockDim.x + threadIdx.x; e < E; e += stride) {
        atomicAdd(&counts[ei[E + e]], 1);   // dst row
    }
}

__global__ void k_scanA(const int* __restrict__ counts, int* __restrict__ bsum, int n) {
    __shared__ int a[256];
    int t = threadIdx.x;
    int i = blockIdx.x * 256 + t;
    a[t] = (i < n) ? counts[i] : 0;
    __syncthreads();
    for (int off = 128; off >= 1; off >>= 1) {
        if (t < off) a[t] += a[t + off];
        __syncthreads();
    }
    if (t == 0) bsum[blockIdx.x] = a[0];
}

__global__ void k_scanB(int* __restrict__ bsum, int nb) {
    __shared__ int a[256];
    __shared__ int carry;
    int t = threadIdx.x;
    if (t == 0) carry = 0;
    __syncthreads();
    for (int base = 0; base < nb; base += 256) {
        int v = (base + t < nb) ? bsum[base + t] : 0;
        a[t] = v;
        __syncthreads();
        for (int off = 1; off < 256; off <<= 1) {
            int x = (t >= off) ? a[t - off] : 0;
            __syncthreads();
            a[t] += x;
            __syncthreads();
        }
        int excl = carry + (t ? a[t - 1] : 0);
        int tot  = carry + a[255];
        if (base + t < nb) bsum[base + t] = excl;
        __syncthreads();
        if (t == 0) carry = tot;
        __syncthreads();
    }
}

__global__ void k_scanC(const int* __restrict__ counts, const int* __restrict__ boff,
                        int* __restrict__ rowst, int* __restrict__ cursor, int n) {
    __shared__ int a[256];
    int t = threadIdx.x;
    int i = blockIdx.x * 256 + t;
    int v = (i < n) ? counts[i] : 0;
    a[t] = v;
    __syncthreads();
    for (int off = 1; off < 256; off <<= 1) {
        int x = (t >= off) ? a[t - off] : 0;
        __syncthreads();
        a[t] += x;
        __syncthreads();
    }
    int excl = boff[blockIdx.x] + (t ? a[t - 1] : 0);
    if (i < n) { rowst[i] = excl; cursor[i] = excl; }
}

// ---------------- XCD-grouped scatter ----------------
__global__ void k_scatter(const int* __restrict__ ei, const float* __restrict__ ew,
                          int* __restrict__ cursor, int2* __restrict__ pairs, int E) {
    const int group = blockIdx.x & 7;
    int e = (blockIdx.x >> 3) * blockDim.x + threadIdx.x;
    const int stride = (gridDim.x >> 3) * blockDim.x;
    for (; e < E; e += stride) {
        int d = ei[E + e];
        if (((d >> 6) & 7) == group) {
            int pos = atomicAdd(&cursor[d], 1);
            pairs[pos] = make_int2(ei[e], __float_as_int(ew[e]));
        }
    }
}

// ---------------- aggregation: wave-per-node, lane=feature, bf16 gathers ----
// Gathers 2B/lane -> ONE 128B line per edge (vs two for fp32). Self term fp32.
__global__ void k_agg(const unsigned short* __restrict__ hb,
                      const float* __restrict__ h,
                      const int* __restrict__ rowst,
                      const int* __restrict__ counts, const int2* __restrict__ pairs,
                      float* __restrict__ out, int N) {
    const int lane = threadIdx.x & 63;
    int wave = (blockIdx.x * blockDim.x + threadIdx.x) >> 6;
    const int nwaves = (gridDim.x * blockDim.x) >> 6;
    for (int node = wave; node < N; node += nwaves) {
        int un = __builtin_amdgcn_readfirstlane(node);
        int s = rowst[un];
        int end = s + counts[un];
        float a0 = 0.f, a1 = 0.f, a2 = 0.f, a3 = 0.f;
        float a4 = 0.f, a5 = 0.f, a6 = 0.f, a7 = 0.f;
        int e = s;
        for (; e + 7 < end; e += 8) {
            int2 p0 = pairs[e],     p1 = pairs[e + 1], p2 = pairs[e + 2], p3 = pairs[e + 3];
            int2 p4 = pairs[e + 4], p5 = pairs[e + 5], p6 = pairs[e + 6], p7 = pairs[e + 7];
            unsigned short v0 = hb[(size_t)p0.x * EMB + lane];
            unsigned short v1 = hb[(size_t)p1.x * EMB + lane];
            unsigned short v2 = hb[(size_t)p2.x * EMB + lane];
            unsigned short v3 = hb[(size_t)p3.x * EMB + lane];
            unsigned short v4 = hb[(size_t)p4.x * EMB + lane];
            unsigned short v5 = hb[(size_t)p5.x * EMB + lane];
            unsigned short v6 = hb[(size_t)p6.x * EMB + lane];
            unsigned short v7 = hb[(size_t)p7.x * EMB + lane];
            a0 = fmaf(__int_as_float(p0.y), b2f(v0), a0);
            a1 = fmaf(__int_as_float(p1.y), b2f(v1), a1);
            a2 = fmaf(__int_as_float(p2.y), b2f(v2), a2);
            a3 = fmaf(__int_as_float(p3.y), b2f(v3), a3);
            a4 = fmaf(__int_as_float(p4.y), b2f(v4), a4);
            a5 = fmaf(__int_as_float(p5.y), b2f(v5), a5);
            a6 = fmaf(__int_as_float(p6.y), b2f(v6), a6);
            a7 = fmaf(__int_as_float(p7.y), b2f(v7), a7);
        }
        for (; e < end; e++) {
            int2 p0 = pairs[e];
            a0 = fmaf(__int_as_float(p0.y), b2f(hb[(size_t)p0.x * EMB + lane]), a0);
        }
        float self = h[(size_t)un * EMB + lane];
        out[(size_t)un * EMB + lane] =
            (((a0 + a1) + (a2 + a3)) + ((a4 + a5) + (a6 + a7))) + self;
    }
}

// ---------------- matmul: wave = 64 nodes x 64 cols, fused BN-in + stats ----
// B16OUT: also emit packed bf16 copy of the output (for the gather path).
template <bool BN_IN, bool DO_STATS>
__global__ void __launch_bounds__(128) k_mm(
                     const float* __restrict__ in, const float* __restrict__ W,
                     const float* __restrict__ bias, const float* __restrict__ stats,
                     const float* __restrict__ g, const float* __restrict__ be,
                     float invN, float* __restrict__ out, float* __restrict__ st_out,
                     unsigned short* __restrict__ b16out, int N) {
    __shared__ float tilebuf[2][64 * TB_STRIDE];
    __shared__ float st_part[128];
    const int tid = threadIdx.x;
    const int lane = tid & 63;
    float* tb = tilebuf[tid >> 6];
    if (DO_STATS) {
        st_part[tid] = 0.f;
        __syncthreads();
    }
    float s_sum = 0.f, s_sq = 0.f;

    int wv = (blockIdx.x * blockDim.x + tid) >> 6;
    const int nwv = (gridDim.x * blockDim.x) >> 6;
    const int ntiles = (N + 63) >> 6;
    for (int tile = wv; tile < ntiles; tile += nwv) {
        int utile = __builtin_amdgcn_readfirstlane(tile);
        int node = utile * 64 + lane;
        bool valid = node < N;

        float row[EMB];
        if (valid) {
            const float4* in4 = (const float4*)(in + (size_t)node * EMB);
#pragma unroll
            for (int i = 0; i < 16; i++) {
                float4 v = in4[i];
                row[4 * i + 0] = v.x; row[4 * i + 1] = v.y;
                row[4 * i + 2] = v.z; row[4 * i + 3] = v.w;
            }
        } else {
#pragma unroll
            for (int i = 0; i < EMB; i++) row[i] = 0.f;
        }

        if (BN_IN) {
#pragma unroll
            for (int f = 0; f < EMB; f++) {
                float m  = stats[f] * invN;
                float va = fmaf(stats[EMB + f], invN, -m * m);
                float rs = rsqrtf(va + BN_EPS);
                float sc = rs * g[f];
                float sh = fmaf(-m, sc, be[f]);
                row[f] = fmaxf(0.f, fmaf(row[f], sc, sh));
            }
        }

        for (int jc = 0; jc < 8; jc++) {
            int j0 = jc * 8;
            float acc[8];
#pragma unroll
            for (int k = 0; k < 8; k++) acc[k] = bias[j0 + k];
#pragma unroll
            for (int f = 0; f < EMB; f++) {
                const float* wr = W + f * EMB + j0;   // uniform -> s_load
#pragma unroll
                for (int k = 0; k < 8; k++) acc[k] = fmaf(row[f], wr[k], acc[k]);
            }
#pragma unroll
            for (int k = 0; k < 8; k++)
                tb[lane * TB_STRIDE + j0 + k] = valid ? acc[k] : 0.f;
        }

        if (DO_STATS) {
#pragma unroll 8
            for (int nn = 0; nn < 64; nn++) {
                float v = tb[nn * TB_STRIDE + lane];
                s_sum += v;
                s_sq = fmaf(v, v, s_sq);
            }
        }

        const int tbase = utile * 64;
        float4* out4 = (float4*)out + (size_t)tbase * 16;
#pragma unroll
        for (int it = 0; it < 16; it++) {
            int flat4 = it * 64 + lane;
            int nsub = flat4 >> 4;
            int c4 = flat4 & 15;
            if (tbase + nsub < N) {
                const float* s4 = tb + nsub * TB_STRIDE + c4 * 4;
                float4 o = make_float4(s4[0], s4[1], s4[2], s4[3]);
                out4[flat4] = o;
                if (b16out) {
                    ushort4 ob;
                    ob.x = f2b(o.x); ob.y = f2b(o.y);
                    ob.z = f2b(o.z); ob.w = f2b(o.w);
                    ((ushort4*)b16out)[(size_t)tbase * 16 + flat4] = ob;
                }
            }
        }
    }

    if (DO_STATS) {
        atomicAdd(&st_part[lane], s_sum);
        atomicAdd(&st_part[64 + lane], s_sq);
        __syncthreads();
        if (tid < 128) atomicAdd(&st_out[tid], st_part[tid]);
    }
}

// ---------------- outer BN + relu + residual (+ bf16 copy) ----------------
__global__ void k_bnres(const float* __restrict__ u, const float* __restrict__ st,
                        const float* __restrict__ g, const float* __restrict__ be,
                        const float* __restrict__ hin, float* __restrict__ hout,
                        unsigned short* __restrict__ b16out,
                        float invN, int total4) {
    int stride = gridDim.x * blockDim.x;
    for (int i4 = blockIdx.x * blockDim.x + threadIdx.x; i4 < total4; i4 += stride) {
        int c = i4 & 15;
        float4 uv = ((const float4*)u)[i4];
        float4 hv = ((const float4*)hin)[i4];
        float4 sv = ((const float4*)st)[c];
        float4 qv = ((const float4*)(st + EMB))[c];
        float4 gv = ((const float4*)g)[c];
        float4 bv = ((const float4*)be)[c];
        float4 o;
#define BNR(comp)                                                     \
        {                                                             \
            float m  = sv.comp * invN;                                \
            float va = fmaf(qv.comp, invN, -m * m);                   \
            float rs = rsqrtf(va + BN_EPS);                           \
            float sc = rs * gv.comp;                                  \
            float sh = fmaf(-m, sc, bv.comp);                         \
            float r  = fmaxf(0.f, fmaf(uv.comp, sc, sh));             \
            o.comp = r + hv.comp;                                     \
        }
        BNR(x) BNR(y) BNR(z) BNR(w)
#undef BNR
        ((float4*)hout)[i4] = o;
        if (b16out) {
            ushort4 ob;
            ob.x = f2b(o.x); ob.y = f2b(o.y);
            ob.z = f2b(o.z); ob.w = f2b(o.w);
            ((ushort4*)b16out)[i4] = ob;
        }
    }
}

// ---------------- launcher ----------------
extern "C" void kernel_launch(void* const* d_in, const int* in_sizes, int n_in,
                              void* d_out, int out_size, void* d_ws, size_t ws_size,
                              hipStream_t stream) {
    const float* x     = (const float*)d_in[0];
    const int*   ei    = (const int*)d_in[1];
    const float* ew    = (const float*)d_in[3];
    const float* ae_w  = (const float*)d_in[4];
    const float* ae_b  = (const float*)d_in[5];
    const float* W1    = (const float*)d_in[6];
    const float* b1    = (const float*)d_in[7];
    const float* g1    = (const float*)d_in[8];
    const float* be1   = (const float*)d_in[9];
    const float* W2    = (const float*)d_in[10];
    const float* b2    = (const float*)d_in[11];
    const float* g_out = (const float*)d_in[12];
    const float* be_out= (const float*)d_in[13];

    const int N = in_sizes[0] / EMB;
    const int E = in_sizes[3];
    const int L = in_sizes[6] / (EMB * EMB);
    const float invN = 1.0f / (float)N;

    uintptr_t p = (uintptr_t)d_ws;
    auto alloc = [&](size_t bytes) -> void* {
        p = (p + 255) & ~(uintptr_t)255;
        void* r = (void*)p;
        p += bytes;
        return r;
    };
    float* h     = (float*)alloc((size_t)N * EMB * 4);
    float* bufa  = (float*)alloc((size_t)N * EMB * 4);
    float* buft  = (float*)alloc((size_t)N * EMB * 4);
    unsigned short* hb16 = (unsigned short*)alloc((size_t)N * EMB * 2);
    int*   counts= (int*)alloc((size_t)N * 4);
    int*   rowst = (int*)alloc((size_t)N * 4);
    int*   cursor= (int*)alloc((size_t)N * 4);
    const int NB = (N + 255) / 256;
    int*   bsum  = (int*)alloc((size_t)NB * 4);
    int2*  pairs = (int2*)alloc((size_t)E * 8);
    float* stats = (float*)alloc((size_t)L * 2 * 2 * EMB * 4);
    (void)ws_size; (void)n_in; (void)out_size;

    const int nstats = L * 2 * 2 * EMB;
    int zgrid = ((N > nstats ? N : nstats) + 255) / 256;
    hipLaunchKernelGGL(k_zero, dim3(zgrid), dim3(256), 0, stream, counts, stats, N, nstats);

    const int ntiles = (N + 63) / 64;
    const int mmgrid = (ntiles + 1) / 2;
    // encoder: h = x @ ae_w + ae_b   (+ bf16 copy)
    hipLaunchKernelGGL((k_mm<false, false>), dim3(mmgrid), dim3(128), 0, stream,
                       x, ae_w, ae_b, (const float*)nullptr, (const float*)nullptr,
                       (const float*)nullptr, 0.f, h, (float*)nullptr, hb16, N);

    // CSR build
    const int eg = (E + 255) / 256;
    hipLaunchKernelGGL(k_hist,  dim3(eg), dim3(256), 0, stream, ei, counts, E);
    hipLaunchKernelGGL(k_scanA, dim3(NB), dim3(256), 0, stream, counts, bsum, N);
    hipLaunchKernelGGL(k_scanB, dim3(1),  dim3(256), 0, stream, bsum, NB);
    hipLaunchKernelGGL(k_scanC, dim3(NB), dim3(256), 0, stream, counts, bsum, rowst, cursor, N);
    hipLaunchKernelGGL(k_scatter, dim3(512), dim3(256), 0, stream, ei, ew, cursor, pairs, E);

    for (int l = 0; l < L; l++) {
        float* stats1 = stats + (size_t)(l * 2 + 0) * 2 * EMB;
        float* stats2 = stats + (size_t)(l * 2 + 1) * 2 * EMB;

        // agg + self  (bf16 gathers)
        hipLaunchKernelGGL(k_agg, dim3(2048), dim3(256), 0, stream,
                           hb16, h, rowst, counts, pairs, bufa, N);
        // t = agg @ W1 + b1   (+stats1)
        hipLaunchKernelGGL((k_mm<false, true>), dim3(mmgrid), dim3(128), 0, stream,
                           bufa, W1 + (size_t)l * EMB * EMB, b1 + (size_t)l * EMB,
                           (const float*)nullptr, (const float*)nullptr,
                           (const float*)nullptr, 0.f, buft, stats1,
                           (unsigned short*)nullptr, N);
        // u = relu(bn1(t)) @ W2 + b2   (+stats2)
        hipLaunchKernelGGL((k_mm<true, true>), dim3(mmgrid), dim3(128), 0, stream,
                           buft, W2 + (size_t)l * EMB * EMB, b2 + (size_t)l * EMB,
                           stats1, g1 + (size_t)l * EMB, be1 + (size_t)l * EMB,
                           invN, bufa, stats2, (unsigned short*)nullptr, N);
        // h = relu(bn2(u)) + h   (+ bf16 copy for next layer's gathers)
        float* hout = (l == L - 1) ? (float*)d_out : h;
        unsigned short* b16o = (l == L - 1) ? (unsigned short*)nullptr : hb16;
        hipLaunchKernelGGL(k_bnres, dim3(1024), dim3(256), 0, stream,
                           bufa, stats2, g_out + (size_t)l * EMB, be_out + (size_t)l * EMB,
                           h, hout, b16o, invN, N * 16);
    }
}

// Round 7
// 589.589 us; speedup vs baseline: 1.4745x; 1.0148x over previous
//
#include <hip/hip_runtime.h>
#include <stdint.h>

#define EMB 64
#define BN_EPS 1e-5f
#define TB_STRIDE 65
#define BSH 8              // bucket = 256 consecutive dst nodes
#define CHUNK 4096         // edges per k_part block

__device__ __forceinline__ unsigned short f2b(float x) {
    unsigned u = __float_as_uint(x);
    u += 0x7FFFu + ((u >> 16) & 1u);   // round-to-nearest-even
    return (unsigned short)(u >> 16);
}
__device__ __forceinline__ float b2f(unsigned short v) {
    return __uint_as_float(((unsigned)v) << 16);
}

// ---------------- zero init (ws is poisoned 0xAA every call) ----------------
__global__ void k_zero(int* __restrict__ bcnt, float* __restrict__ stats,
                       int nb, int nstats) {
    int i = blockIdx.x * blockDim.x + threadIdx.x;
    if (i < nb) bcnt[i] = 0;
    if (i < nstats) stats[i] = 0.0f;
}

// ---------------- bucket histogram (dst read once, LDS-combined) ----------
__global__ void __launch_bounds__(256) k_bhist(const int* __restrict__ ei,
                                               int* __restrict__ bcnt,
                                               int E, int nb) {
    __shared__ int lh[256];
    const int tid = threadIdx.x;
    lh[tid] = 0;
    __syncthreads();
    int stride = gridDim.x * blockDim.x;
    for (int e = blockIdx.x * blockDim.x + tid; e < E; e += stride)
        atomicAdd(&lh[((unsigned)ei[E + e]) >> BSH], 1);
    __syncthreads();
    if (tid < nb && lh[tid]) atomicAdd(&bcnt[tid], lh[tid]);
}

// ---------------- single-block bucket scan ----------------
__global__ void __launch_bounds__(256) k_bscan(const int* __restrict__ bcnt,
                                               int* __restrict__ bbase,
                                               int* __restrict__ bcur, int nb) {
    __shared__ int a[256];
    const int t = threadIdx.x;
    int v = (t < nb) ? bcnt[t] : 0;
    a[t] = v;
    __syncthreads();
    for (int off = 1; off < 256; off <<= 1) {
        int x = (t >= off) ? a[t - off] : 0;
        __syncthreads();
        a[t] += x;
        __syncthreads();
    }
    int excl = a[t] - v;
    if (t < nb) { bbase[t] = excl; bcur[t] = excl; }
    if (t == nb - 1) bbase[nb] = a[t];
}

// ---------------- phase 1: compact edges into per-bucket runs --------------
// Each block bins its 4096-edge chunk in LDS, reserves one contiguous run per
// bucket via a single global atomic, then appends (full-line writes).
__global__ void __launch_bounds__(256) k_part(
        const int* __restrict__ ei, const float* __restrict__ ew,
        int* __restrict__ bcur, int2* __restrict__ eG, int E) {
    __shared__ int lcnt[256], lbase[256], loff[256];
    const int tid = threadIdx.x;
    const int c0 = blockIdx.x * CHUNK;
    lcnt[tid] = 0;
    __syncthreads();
    int src[16], pk[16], g[16];
    float wt[16];
#pragma unroll
    for (int i = 0; i < 16; i++) {
        int e = c0 + i * 256 + tid;
        if (e < E) {
            int d = ei[E + e];
            src[i] = ei[e];
            wt[i] = ew[e];
            g[i] = ((unsigned)d) >> BSH;
            pk[i] = src[i] | ((d & 255) << 24);
            atomicAdd(&lcnt[g[i]], 1);
        } else g[i] = -1;
    }
    __syncthreads();
    if (lcnt[tid]) lbase[tid] = atomicAdd(&bcur[tid], lcnt[tid]);
    loff[tid] = 0;
    __syncthreads();
#pragma unroll
    for (int i = 0; i < 16; i++) {
        if (g[i] >= 0) {
            int pos = lbase[g[i]] + atomicAdd(&loff[g[i]], 1);
            eG[pos] = make_int2(pk[i], __float_as_int(wt[i]));
        }
    }
}

// ---------------- phase 2: exact CSR inside each bucket --------------------
// One block per bucket. LDS per-node histogram + scan -> rowst/counts; then
// place pairs within the bucket's private ~32KB region (single XCD, L2-hot).
__global__ void __launch_bounds__(256) k_build(
        const int2* __restrict__ eG, const int* __restrict__ bbase,
        int* __restrict__ rowst, int* __restrict__ counts,
        int2* __restrict__ pairs, int N) {
    __shared__ int lcnt[256], a[256], lcur[256];
    const int t = threadIdx.x;
    const int b = blockIdx.x;
    const int e0 = bbase[b], e1 = bbase[b + 1];
    lcnt[t] = 0;
    __syncthreads();
    for (int i = e0 + t; i < e1; i += 256)
        atomicAdd(&lcnt[((unsigned)eG[i].x) >> 24], 1);
    __syncthreads();
    int v = lcnt[t];
    a[t] = v;
    __syncthreads();
    for (int off = 1; off < 256; off <<= 1) {
        int x = (t >= off) ? a[t - off] : 0;
        __syncthreads();
        a[t] += x;
        __syncthreads();
    }
    int excl = a[t] - v;
    lcur[t] = excl;
    int node = (b << BSH) + t;
    if (node < N) { rowst[node] = e0 + excl; counts[node] = v; }
    __syncthreads();
    for (int i = e0 + t; i < e1; i += 256) {
        int2 p = eG[i];
        int loc = ((unsigned)p.x) >> 24;
        int pos = e0 + atomicAdd(&lcur[loc], 1);
        pairs[pos] = make_int2(p.x & 0x00FFFFFF, p.y);
    }
}

// ---------------- aggregation: wave-per-node, lane=feature, bf16 gathers ----
// Masked 8-wide loop: no serial scalar tail; OOB slots clamp to the row's
// first edge with weight forced to 0 (line already hot).
__global__ void k_agg(const unsigned short* __restrict__ hb,
                      const float* __restrict__ h,
                      const int* __restrict__ rowst,
                      const int* __restrict__ counts, const int2* __restrict__ pairs,
                      float* __restrict__ out, int N) {
    const int lane = threadIdx.x & 63;
    int wave = (blockIdx.x * blockDim.x + threadIdx.x) >> 6;
    const int nwaves = (gridDim.x * blockDim.x) >> 6;
    for (int node = wave; node < N; node += nwaves) {
        int un = __builtin_amdgcn_readfirstlane(node);
        int s = rowst[un];
        int end = s + counts[un];
        float a0 = 0.f, a1 = 0.f, a2 = 0.f, a3 = 0.f;
        float a4 = 0.f, a5 = 0.f, a6 = 0.f, a7 = 0.f;
        for (int e = s; e < end; e += 8) {
#define SLOT(K, ACC)                                                       \
            {                                                              \
                int idx = e + K;                                           \
                bool ok = idx < end;                                       \
                int2 p = pairs[ok ? idx : s];                              \
                float w = ok ? __int_as_float(p.y) : 0.f;                  \
                float vv = b2f(hb[(size_t)p.x * EMB + lane]);              \
                ACC = fmaf(w, vv, ACC);                                    \
            }
            SLOT(0, a0) SLOT(1, a1) SLOT(2, a2) SLOT(3, a3)
            SLOT(4, a4) SLOT(5, a5) SLOT(6, a6) SLOT(7, a7)
#undef SLOT
        }
        float self = h[(size_t)un * EMB + lane];
        out[(size_t)un * EMB + lane] =
            (((a0 + a1) + (a2 + a3)) + ((a4 + a5) + (a6 + a7))) + self;
    }
}

// ---------------- matmul: wave = 64 nodes x 64 cols, fused BN-in + stats ----
template <bool BN_IN, bool DO_STATS>
__global__ void __launch_bounds__(128) k_mm(
                     const float* __restrict__ in, const float* __restrict__ W,
                     const float* __restrict__ bias, const float* __restrict__ stats,
                     const float* __restrict__ g, const float* __restrict__ be,
                     float invN, float* __restrict__ out, float* __restrict__ st_out,
                     unsigned short* __restrict__ b16out, int N) {
    __shared__ float tilebuf[2][64 * TB_STRIDE];
    __shared__ float st_part[128];
    const int tid = threadIdx.x;
    const int lane = tid & 63;
    float* tb = tilebuf[tid >> 6];
    if (DO_STATS) {
        st_part[tid] = 0.f;
        __syncthreads();
    }
    float s_sum = 0.f, s_sq = 0.f;

    int wv = (blockIdx.x * blockDim.x + tid) >> 6;
    const int nwv = (gridDim.x * blockDim.x) >> 6;
    const int ntiles = (N + 63) >> 6;
    for (int tile = wv; tile < ntiles; tile += nwv) {
        int utile = __builtin_amdgcn_readfirstlane(tile);
        int node = utile * 64 + lane;
        bool valid = node < N;

        float row[EMB];
        if (valid) {
            const float4* in4 = (const float4*)(in + (size_t)node * EMB);
#pragma unroll
            for (int i = 0; i < 16; i++) {
                float4 v = in4[i];
                row[4 * i + 0] = v.x; row[4 * i + 1] = v.y;
                row[4 * i + 2] = v.z; row[4 * i + 3] = v.w;
            }
        } else {
#pragma unroll
            for (int i = 0; i < EMB; i++) row[i] = 0.f;
        }

        if (BN_IN) {
#pragma unroll
            for (int f = 0; f < EMB; f++) {
                float m  = stats[f] * invN;
                float va = fmaf(stats[EMB + f], invN, -m * m);
                float rs = rsqrtf(va + BN_EPS);
                float sc = rs * g[f];
                float sh = fmaf(-m, sc, be[f]);
                row[f] = fmaxf(0.f, fmaf(row[f], sc, sh));
            }
        }

        for (int jc = 0; jc < 8; jc++) {
            int j0 = jc * 8;
            float acc[8];
#pragma unroll
            for (int k = 0; k < 8; k++) acc[k] = bias[j0 + k];
#pragma unroll
            for (int f = 0; f < EMB; f++) {
                const float* wr = W + f * EMB + j0;   // uniform -> s_load
#pragma unroll
                for (int k = 0; k < 8; k++) acc[k] = fmaf(row[f], wr[k], acc[k]);
            }
#pragma unroll
            for (int k = 0; k < 8; k++)
                tb[lane * TB_STRIDE + j0 + k] = valid ? acc[k] : 0.f;
        }

        if (DO_STATS) {
#pragma unroll 8
            for (int nn = 0; nn < 64; nn++) {
                float v = tb[nn * TB_STRIDE + lane];
                s_sum += v;
                s_sq = fmaf(v, v, s_sq);
            }
        }

        const int tbase = utile * 64;
        float4* out4 = (float4*)out + (size_t)tbase * 16;
#pragma unroll
        for (int it = 0; it < 16; it++) {
            int flat4 = it * 64 + lane;
            int nsub = flat4 >> 4;
            int c4 = flat4 & 15;
            if (tbase + nsub < N) {
                const float* s4 = tb + nsub * TB_STRIDE + c4 * 4;
                float4 o = make_float4(s4[0], s4[1], s4[2], s4[3]);
                out4[flat4] = o;
                if (b16out) {
                    ushort4 ob;
                    ob.x = f2b(o.x); ob.y = f2b(o.y);
                    ob.z = f2b(o.z); ob.w = f2b(o.w);
                    ((ushort4*)b16out)[(size_t)tbase * 16 + flat4] = ob;
                }
            }
        }
    }

    if (DO_STATS) {
        atomicAdd(&st_part[lane], s_sum);
        atomicAdd(&st_part[64 + lane], s_sq);
        __syncthreads();
        if (tid < 128) atomicAdd(&st_out[tid], st_part[tid]);
    }
}

// ---------------- outer BN + relu + residual (+ bf16 copy) ----------------
__global__ void k_bnres(const float* __restrict__ u, const float* __restrict__ st,
                        const float* __restrict__ g, const float* __restrict__ be,
                        const float* __restrict__ hin, float* __restrict__ hout,
                        unsigned short* __restrict__ b16out,
                        float invN, int total4) {
    int stride = gridDim.x * blockDim.x;
    for (int i4 = blockIdx.x * blockDim.x + threadIdx.x; i4 < total4; i4 += stride) {
        int c = i4 & 15;
        float4 uv = ((const float4*)u)[i4];
        float4 hv = ((const float4*)hin)[i4];
        float4 sv = ((const float4*)st)[c];
        float4 qv = ((const float4*)(st + EMB))[c];
        float4 gv = ((const float4*)g)[c];
        float4 bv = ((const float4*)be)[c];
        float4 o;
#define BNR(comp)                                                     \
        {                                                             \
            float m  = sv.comp * invN;                                \
            float va = fmaf(qv.comp, invN, -m * m);                   \
            float rs = rsqrtf(va + BN_EPS);                           \
            float sc = rs * gv.comp;                                  \
            float sh = fmaf(-m, sc, bv.comp);                         \
            float r  = fmaxf(0.f, fmaf(uv.comp, sc, sh));             \
            o.comp = r + hv.comp;                                     \
        }
        BNR(x) BNR(y) BNR(z) BNR(w)
#undef BNR
        ((float4*)hout)[i4] = o;
        if (b16out) {
            ushort4 ob;
            ob.x = f2b(o.x); ob.y = f2b(o.y);
            ob.z = f2b(o.z); ob.w = f2b(o.w);
            ((ushort4*)b16out)[i4] = ob;
        }
    }
}

// ---------------- launcher ----------------
extern "C" void kernel_launch(void* const* d_in, const int* in_sizes, int n_in,
                              void* d_out, int out_size, void* d_ws, size_t ws_size,
                              hipStream_t stream) {
    const float* x     = (const float*)d_in[0];
    const int*   ei    = (const int*)d_in[1];
    const float* ew    = (const float*)d_in[3];
    const float* ae_w  = (const float*)d_in[4];
    const float* ae_b  = (const float*)d_in[5];
    const float* W1    = (const float*)d_in[6];
    const float* b1    = (const float*)d_in[7];
    const float* g1    = (const float*)d_in[8];
    const float* be1   = (const float*)d_in[9];
    const float* W2    = (const float*)d_in[10];
    const float* b2    = (const float*)d_in[11];
    const float* g_out = (const float*)d_in[12];
    const float* be_out= (const float*)d_in[13];

    const int N = in_sizes[0] / EMB;
    const int E = in_sizes[3];
    const int L = in_sizes[6] / (EMB * EMB);
    const float invN = 1.0f / (float)N;
    const int NBUCK = (N + 255) >> BSH;   // <=256 (N<=65536)

    uintptr_t p = (uintptr_t)d_ws;
    auto alloc = [&](size_t bytes) -> void* {
        p = (p + 255) & ~(uintptr_t)255;
        void* r = (void*)p;
        p += bytes;
        return r;
    };
    float* h     = (float*)alloc((size_t)N * EMB * 4);
    float* bufa  = (float*)alloc((size_t)N * EMB * 4);
    float* buft  = (float*)alloc((size_t)N * EMB * 4);  // also hosts staged edges
    unsigned short* hb16 = (unsigned short*)alloc((size_t)N * EMB * 2);
    int*   counts= (int*)alloc((size_t)N * 4);
    int*   rowst = (int*)alloc((size_t)N * 4);
    int*   bcnt  = (int*)alloc(256 * 4);
    int*   bbase = (int*)alloc(257 * 4);
    int*   bcur  = (int*)alloc(256 * 4);
    int2*  pairs = (int2*)alloc((size_t)E * 8);
    float* stats = (float*)alloc((size_t)L * 2 * 2 * EMB * 4);
    int2*  eG    = (int2*)buft;           // staged edges (dead until mm1)
    (void)ws_size; (void)n_in; (void)out_size;

    const int nstats = L * 2 * 2 * EMB;
    int zgrid = ((NBUCK > nstats ? NBUCK : nstats) + 255) / 256;
    hipLaunchKernelGGL(k_zero, dim3(zgrid), dim3(256), 0, stream,
                       bcnt, stats, NBUCK, nstats);

    const int ntiles = (N + 63) / 64;
    const int mmgrid = (ntiles + 1) / 2;
    // encoder: h = x @ ae_w + ae_b   (+ bf16 copy)
    hipLaunchKernelGGL((k_mm<false, false>), dim3(mmgrid), dim3(128), 0, stream,
                       x, ae_w, ae_b, (const float*)nullptr, (const float*)nullptr,
                       (const float*)nullptr, 0.f, h, (float*)nullptr, hb16, N);

    // CSR build: bucket hist -> scan -> compact -> per-bucket exact CSR
    hipLaunchKernelGGL(k_bhist, dim3(120), dim3(256), 0, stream, ei, bcnt, E, NBUCK);
    hipLaunchKernelGGL(k_bscan, dim3(1), dim3(256), 0, stream, bcnt, bbase, bcur, NBUCK);
    hipLaunchKernelGGL(k_part, dim3((E + CHUNK - 1) / CHUNK), dim3(256), 0, stream,
                       ei, ew, bcur, eG, E);
    hipLaunchKernelGGL(k_build, dim3(NBUCK), dim3(256), 0, stream,
                       eG, bbase, rowst, counts, pairs, N);

    for (int l = 0; l < L; l++) {
        float* stats1 = stats + (size_t)(l * 2 + 0) * 2 * EMB;
        float* stats2 = stats + (size_t)(l * 2 + 1) * 2 * EMB;

        // agg + self  (bf16 gathers)
        hipLaunchKernelGGL(k_agg, dim3(2048), dim3(256), 0, stream,
                           hb16, h, rowst, counts, pairs, bufa, N);
        // t = agg @ W1 + b1   (+stats1)
        hipLaunchKernelGGL((k_mm<false, true>), dim3(mmgrid), dim3(128), 0, stream,
                           bufa, W1 + (size_t)l * EMB * EMB, b1 + (size_t)l * EMB,
                           (const float*)nullptr, (const float*)nullptr,
                           (const float*)nullptr, 0.f, buft, stats1,
                           (unsigned short*)nullptr, N);
        // u = relu(bn1(t)) @ W2 + b2   (+stats2)
        hipLaunchKernelGGL((k_mm<true, true>), dim3(mmgrid), dim3(128), 0, stream,
                           buft, W2 + (size_t)l * EMB * EMB, b2 + (size_t)l * EMB,
                           stats1, g1 + (size_t)l * EMB, be1 + (size_t)l * EMB,
                           invN, bufa, stats2, (unsigned short*)nullptr, N);
        // h = relu(bn2(u)) + h   (+ bf16 copy for next layer's gathers)
        float* hout = (l == L - 1) ? (float*)d_out : h;
        unsigned short* b16o = (l == L - 1) ? (unsigned short*)nullptr : hb16;
        hipLaunchKernelGGL(k_bnres, dim3(1024), dim3(256), 0, stream,
                           bufa, stats2, g_out + (size_t)l * EMB, be_out + (size_t)l * EMB,
                           h, hout, b16o, invN, N * 16);
    }
}